// Round 1
// baseline (928.945 us; speedup 1.0000x reference)
//
#include <hip/hip_runtime.h>
#include <hip/hip_bf16.h>
#include <math.h>

// Problem constants (GPT2Attention: B=2, T=2048, EMBED=768, 12 heads, head=64)
#define NB      2
#define T_SZ    2048
#define EMBEDC  768
#define NHEADS  12
#define HEADD   64
#define QKV_PER (NB * NHEADS * T_SZ * HEADD)   // 3,145,728 floats per q/k/v

// ---------------------------------------------------------------------------
// Tiled f32 GEMM: out = A[MxK] @ W[KxN] (+bias), 128x128 tile, BK=16,
// 256 threads, 8x8 accumulators per thread.
// MODE 0: linear store out[m*N+n] = acc + bias[n]
// MODE 1: QKV scatter into [mat][b*12+head][t][hd] (head = c%12 is the INNER
//         channel factor per the reference's reshape(b,t,HEAD,N_HEADS)).
// ---------------------------------------------------------------------------
template <int MODE>
__global__ __launch_bounds__(256) void gemm_f32_k(
    const float* __restrict__ A, const float* __restrict__ W,
    const float* __restrict__ bias, float* __restrict__ out,
    int M, int N, int K)
{
    __shared__ float As[16][128];   // As[k][m]
    __shared__ float Bs[16][128];   // Bs[k][n]

    const int tid = threadIdx.x;
    const int tx = tid & 15, ty = tid >> 4;
    const int m0 = blockIdx.y * 128, n0 = blockIdx.x * 128;

    float acc[8][8];
#pragma unroll
    for (int i = 0; i < 8; ++i)
#pragma unroll
        for (int j = 0; j < 8; ++j) acc[i][j] = 0.f;

    for (int k0 = 0; k0 < K; k0 += 16) {
        // Stage A tile 128x16 (transposed into As[k][m])
#pragma unroll
        for (int u = 0; u < 2; ++u) {
            int f = tid + u * 256;          // 0..511 float4 slots
            int row = f >> 2, kq = f & 3;
            float4 v = *(const float4*)(A + (size_t)(m0 + row) * K + k0 + kq * 4);
            As[kq * 4 + 0][row] = v.x;
            As[kq * 4 + 1][row] = v.y;
            As[kq * 4 + 2][row] = v.z;
            As[kq * 4 + 3][row] = v.w;
        }
        // Stage B tile 16x128 (row-major, coalesced float4)
#pragma unroll
        for (int u = 0; u < 2; ++u) {
            int f = tid + u * 256;
            int kr = f >> 5, nq = f & 31;
            *(float4*)&Bs[kr][nq * 4] =
                *(const float4*)(W + (size_t)(k0 + kr) * N + n0 + nq * 4);
        }
        __syncthreads();

#pragma unroll
        for (int k = 0; k < 16; ++k) {
            // A fragment: rows ty*8..+7 (broadcast across the 16 tx lanes)
            float4 a0 = *(const float4*)&As[k][ty * 8];
            float4 a1 = *(const float4*)&As[k][ty * 8 + 4];
            // B fragment: two stride-64 float4 chunks -> 2-way LDS aliasing (free)
            float4 b0 = *(const float4*)&Bs[k][tx * 4];
            float4 b1 = *(const float4*)&Bs[k][64 + tx * 4];
            float av[8] = {a0.x, a0.y, a0.z, a0.w, a1.x, a1.y, a1.z, a1.w};
            float bv[8] = {b0.x, b0.y, b0.z, b0.w, b1.x, b1.y, b1.z, b1.w};
#pragma unroll
            for (int i = 0; i < 8; ++i)
#pragma unroll
                for (int j = 0; j < 8; ++j)
                    acc[i][j] = fmaf(av[i], bv[j], acc[i][j]);
        }
        __syncthreads();
    }

    // Epilogue. Thread's cols: j<4 -> n0+tx*4+j ; j>=4 -> n0+64+tx*4+(j-4)
#pragma unroll
    for (int i = 0; i < 8; ++i) {
        int m = m0 + ty * 8 + i;
        if (MODE == 0) {
            int nA = n0 + tx * 4;
            int nB = n0 + 64 + tx * 4;
            float4 r0 = make_float4(acc[i][0] + bias[nA + 0], acc[i][1] + bias[nA + 1],
                                    acc[i][2] + bias[nA + 2], acc[i][3] + bias[nA + 3]);
            float4 r1 = make_float4(acc[i][4] + bias[nB + 0], acc[i][5] + bias[nB + 1],
                                    acc[i][6] + bias[nB + 2], acc[i][7] + bias[nB + 3]);
            *(float4*)(out + (size_t)m * N + nA) = r0;
            *(float4*)(out + (size_t)m * N + nB) = r1;
        } else {
            int b = m >> 11;            // m / T_SZ
            int t = m & 2047;           // m % T_SZ
#pragma unroll
            for (int j = 0; j < 8; ++j) {
                int n = n0 + ((j < 4) ? (tx * 4 + j) : (64 + tx * 4 + (j - 4)));
                float val = acc[i][j] + bias[n];
                int mat  = n / EMBEDC;          // 0=q 1=k 2=v
                int c    = n - mat * EMBEDC;
                int head = c % NHEADS;          // inner factor!
                int hd   = c / NHEADS;
                out[(size_t)mat * QKV_PER +
                    (((size_t)(b * NHEADS + head)) * T_SZ + t) * HEADD + hd] = val;
            }
        }
    }
}

// ---------------------------------------------------------------------------
// Flash-style causal attention, f32. Grid: (T/64, B*NHEADS). 256 threads.
// Each thread: 4 q-rows (ty*4+i) x 4 head-cols (tx*4+j). Row state reduced
// across the 16-lane tx group via __shfl_xor. K tile is XOR-swizzled at
// float4 granularity to kill the 16-way bank conflict of per-lane-row reads.
// ---------------------------------------------------------------------------
__global__ __launch_bounds__(256) void attn_f32_k(
    const float* __restrict__ Q, const float* __restrict__ Kp,
    const float* __restrict__ V, float* __restrict__ Out)
{
    __shared__ float Qs[64][64];
    __shared__ float Ks[64][64];   // swizzled: phys col4 = cq ^ ((row>>2)&15)
    __shared__ float Vs[64][64];
    __shared__ float Ps[64][64];

    const int qb = blockIdx.x;
    const int bh = blockIdx.y;
    const int bb = bh / NHEADS, head = bh % NHEADS;
    const int tid = threadIdx.x;
    const int tx = tid & 15, ty = tid >> 4;
    const int q0 = qb * 64;
    const size_t base = (size_t)bh * T_SZ * HEADD;
    const float scale = 0.125f;   // HEAD^-0.5

    // Load + pre-scale Q tile
#pragma unroll
    for (int u = 0; u < 4; ++u) {
        int f = tid + u * 256;
        int row = f >> 4, cq = f & 15;
        float4 v = *(const float4*)(Q + base + (size_t)(q0 + row) * HEADD + cq * 4);
        v.x *= scale; v.y *= scale; v.z *= scale; v.w *= scale;
        *(float4*)&Qs[row][cq * 4] = v;
    }

    float o[4][4];
    float mR[4], lR[4];
#pragma unroll
    for (int i = 0; i < 4; ++i) {
        mR[i] = -1e30f; lR[i] = 0.f;
#pragma unroll
        for (int j = 0; j < 4; ++j) o[i][j] = 0.f;
    }

    for (int kt = 0; kt <= qb; ++kt) {
        const int k0 = kt * 64;
        __syncthreads();   // previous-iter reads of Ks/Vs/Ps done; Qs ready (iter 0)
#pragma unroll
        for (int u = 0; u < 4; ++u) {
            int f = tid + u * 256;
            int row = f >> 4, cq = f & 15;
            int p4 = cq ^ ((row >> 2) & 15);
            *(float4*)&Ks[row][p4 * 4] =
                *(const float4*)(Kp + base + (size_t)(k0 + row) * HEADD + cq * 4);
            *(float4*)&Vs[row][cq * 4] =
                *(const float4*)(V + base + (size_t)(k0 + row) * HEADD + cq * 4);
        }
        __syncthreads();

        // S = (Q*scale) @ K^T for this tile
        float s[4][4];
#pragma unroll
        for (int i = 0; i < 4; ++i)
#pragma unroll
            for (int j = 0; j < 4; ++j) s[i][j] = 0.f;

#pragma unroll
        for (int d = 0; d < 64; d += 4) {
            const int c = d >> 2;
            float4 qv[4], kv[4];
#pragma unroll
            for (int i = 0; i < 4; ++i)
                qv[i] = *(const float4*)&Qs[ty * 4 + i][d];
#pragma unroll
            for (int j = 0; j < 4; ++j)
                kv[j] = *(const float4*)&Ks[tx * 4 + j][((c ^ tx) & 15) * 4];
#pragma unroll
            for (int i = 0; i < 4; ++i)
#pragma unroll
                for (int j = 0; j < 4; ++j)
                    s[i][j] += qv[i].x * kv[j].x + qv[i].y * kv[j].y +
                               qv[i].z * kv[j].z + qv[i].w * kv[j].w;
        }

        // Causal mask only on the diagonal tile
        if (kt == qb) {
#pragma unroll
            for (int i = 0; i < 4; ++i)
#pragma unroll
                for (int j = 0; j < 4; ++j)
                    if (tx * 4 + j > ty * 4 + i) s[i][j] = -1e30f;
        }

        // Online softmax per q-row (16-lane group owns a row)
#pragma unroll
        for (int i = 0; i < 4; ++i) {
            float rm = fmaxf(fmaxf(s[i][0], s[i][1]), fmaxf(s[i][2], s[i][3]));
            rm = fmaxf(rm, __shfl_xor(rm, 1));
            rm = fmaxf(rm, __shfl_xor(rm, 2));
            rm = fmaxf(rm, __shfl_xor(rm, 4));
            rm = fmaxf(rm, __shfl_xor(rm, 8));
            float mNew = fmaxf(mR[i], rm);
            float sc = __expf(mR[i] - mNew);
            float p0 = __expf(s[i][0] - mNew);
            float p1 = __expf(s[i][1] - mNew);
            float p2 = __expf(s[i][2] - mNew);
            float p3 = __expf(s[i][3] - mNew);
            float rs = p0 + p1 + p2 + p3;
            rs += __shfl_xor(rs, 1);
            rs += __shfl_xor(rs, 2);
            rs += __shfl_xor(rs, 4);
            rs += __shfl_xor(rs, 8);
            lR[i] = lR[i] * sc + rs;
            mR[i] = mNew;
            o[i][0] *= sc; o[i][1] *= sc; o[i][2] *= sc; o[i][3] *= sc;
            *(float4*)&Ps[ty * 4 + i][tx * 4] = make_float4(p0, p1, p2, p3);
        }
        __syncthreads();

        // O += P @ V
#pragma unroll
        for (int kk = 0; kk < 64; kk += 4) {
            float pv[4][4], vv[4][4];
#pragma unroll
            for (int i = 0; i < 4; ++i) {
                float4 t = *(const float4*)&Ps[ty * 4 + i][kk];
                pv[i][0] = t.x; pv[i][1] = t.y; pv[i][2] = t.z; pv[i][3] = t.w;
            }
#pragma unroll
            for (int d = 0; d < 4; ++d) {
                float4 t = *(const float4*)&Vs[kk + d][tx * 4];
                vv[d][0] = t.x; vv[d][1] = t.y; vv[d][2] = t.z; vv[d][3] = t.w;
            }
#pragma unroll
            for (int i = 0; i < 4; ++i)
#pragma unroll
                for (int j = 0; j < 4; ++j)
                    o[i][j] += pv[i][0] * vv[0][j] + pv[i][1] * vv[1][j] +
                               pv[i][2] * vv[2][j] + pv[i][3] * vv[3][j];
        }
    }

    // Epilogue: att[b][t][head*64 + h] (head is the OUTER factor on output)
#pragma unroll
    for (int i = 0; i < 4; ++i) {
        float inv = 1.f / lR[i];
        size_t off = ((size_t)(bb * T_SZ + q0 + ty * 4 + i)) * EMBEDC +
                     head * HEADD + tx * 4;
        float4 r = make_float4(o[i][0] * inv, o[i][1] * inv,
                               o[i][2] * inv, o[i][3] * inv);
        *(float4*)(Out + off) = r;
    }
}

// ---------------------------------------------------------------------------
extern "C" void kernel_launch(void* const* d_in, const int* in_sizes, int n_in,
                              void* d_out, int out_size, void* d_ws, size_t ws_size,
                              hipStream_t stream)
{
    const float* x      = (const float*)d_in[0];   // [2,2048,768]
    const float* w_attn = (const float*)d_in[1];   // [768,2304]
    const float* b_attn = (const float*)d_in[2];   // [2304]
    const float* w_proj = (const float*)d_in[3];   // [768,768]
    const float* b_proj = (const float*)d_in[4];   // [768]
    float* out = (float*)d_out;                    // [2,2048,768] f32
    float* ws  = (float*)d_ws;

    // Workspace layout (needs 50,331,648 bytes):
    //   q,k,v: 3 * QKV_PER floats in [b*12+head][t][hd]
    //   att  : QKV_PER floats in [b][t][768]
    float* qkv = ws;
    float* att = ws + (size_t)3 * QKV_PER;

    // K1: qkv = x @ w_attn + b_attn, scattered to per-head layout
    gemm_f32_k<1><<<dim3(2304 / 128, 4096 / 128), 256, 0, stream>>>(
        x, w_attn, b_attn, qkv, NB * T_SZ, 3 * EMBEDC, EMBEDC);

    // K2: causal flash attention per (b,head)
    attn_f32_k<<<dim3(T_SZ / 64, NB * NHEADS), 256, 0, stream>>>(
        qkv, qkv + QKV_PER, qkv + 2 * (size_t)QKV_PER, att);

    // K3: out = att @ w_proj + b_proj
    gemm_f32_k<0><<<dim3(768 / 128, 4096 / 128), 256, 0, stream>>>(
        att, w_proj, b_proj, out, NB * T_SZ, EMBEDC, EMBEDC);
}

// Round 2
// 378.302 us; speedup vs baseline: 2.4556x; 2.4556x over previous
//
#include <hip/hip_runtime.h>
#include <hip/hip_bf16.h>
#include <math.h>

// Problem constants (GPT2Attention: B=2, T=2048, EMBED=768, 12 heads, head=64)
#define NB      2
#define T_SZ    2048
#define EMBEDC  768
#define NHEADS  12
#define HEADD   64
#define QKV_PER (NB * NHEADS * T_SZ * HEADD)   // 3,145,728 elems per q/k/v

typedef __bf16 bf16x8 __attribute__((ext_vector_type(8)));
typedef float  f32x4  __attribute__((ext_vector_type(4)));

__device__ inline ushort f2bf(float x) {
    union { float f; uint u; } v; v.f = x;
    uint r = v.u + 0x7fffu + ((v.u >> 16) & 1u);   // RNE
    return (ushort)(r >> 16);
}

// ---------------------------------------------------------------------------
// Tiled f32 GEMM: out = A[MxK] @ W[KxN] (+bias), 128x128 tile, BK=16,
// 256 threads, 8x8 accumulators per thread.
// MODE 0: linear f32 store out[m*N+n] = acc + bias[n]
// MODE 1: QKV epilogue -> bf16 workspace:
//   q (scaled 0.125): [bh][t][hd]   at ob
//   k               : [bh][t][hd]   at ob + QKV_PER
//   vT              : [bh][hd][t]   at ob + 2*QKV_PER
//   (head = c%12 is the INNER channel factor per the reference reshape)
// ---------------------------------------------------------------------------
template <int MODE>
__global__ __launch_bounds__(256) void gemm_f32_k(
    const float* __restrict__ A, const float* __restrict__ W,
    const float* __restrict__ bias, float* __restrict__ out,
    int M, int N, int K)
{
    __shared__ float As[16][128];   // As[k][m]
    __shared__ float Bs[16][128];   // Bs[k][n]

    const int tid = threadIdx.x;
    const int tx = tid & 15, ty = tid >> 4;
    const int m0 = blockIdx.y * 128, n0 = blockIdx.x * 128;

    float acc[8][8];
#pragma unroll
    for (int i = 0; i < 8; ++i)
#pragma unroll
        for (int j = 0; j < 8; ++j) acc[i][j] = 0.f;

    for (int k0 = 0; k0 < K; k0 += 16) {
#pragma unroll
        for (int u = 0; u < 2; ++u) {
            int f = tid + u * 256;
            int row = f >> 2, kq = f & 3;
            float4 v = *(const float4*)(A + (size_t)(m0 + row) * K + k0 + kq * 4);
            As[kq * 4 + 0][row] = v.x;
            As[kq * 4 + 1][row] = v.y;
            As[kq * 4 + 2][row] = v.z;
            As[kq * 4 + 3][row] = v.w;
        }
#pragma unroll
        for (int u = 0; u < 2; ++u) {
            int f = tid + u * 256;
            int kr = f >> 5, nq = f & 31;
            *(float4*)&Bs[kr][nq * 4] =
                *(const float4*)(W + (size_t)(k0 + kr) * N + n0 + nq * 4);
        }
        __syncthreads();

#pragma unroll
        for (int k = 0; k < 16; ++k) {
            float4 a0 = *(const float4*)&As[k][ty * 8];
            float4 a1 = *(const float4*)&As[k][ty * 8 + 4];
            float4 b0 = *(const float4*)&Bs[k][tx * 4];
            float4 b1 = *(const float4*)&Bs[k][64 + tx * 4];
            float av[8] = {a0.x, a0.y, a0.z, a0.w, a1.x, a1.y, a1.z, a1.w};
            float bv[8] = {b0.x, b0.y, b0.z, b0.w, b1.x, b1.y, b1.z, b1.w};
#pragma unroll
            for (int i = 0; i < 8; ++i)
#pragma unroll
                for (int j = 0; j < 8; ++j)
                    acc[i][j] = fmaf(av[i], bv[j], acc[i][j]);
        }
        __syncthreads();
    }

#pragma unroll
    for (int i = 0; i < 8; ++i) {
        int m = m0 + ty * 8 + i;
        if (MODE == 0) {
            int nA = n0 + tx * 4;
            int nB = n0 + 64 + tx * 4;
            float4 r0 = make_float4(acc[i][0] + bias[nA + 0], acc[i][1] + bias[nA + 1],
                                    acc[i][2] + bias[nA + 2], acc[i][3] + bias[nA + 3]);
            float4 r1 = make_float4(acc[i][4] + bias[nB + 0], acc[i][5] + bias[nB + 1],
                                    acc[i][6] + bias[nB + 2], acc[i][7] + bias[nB + 3]);
            *(float4*)(out + (size_t)m * N + nA) = r0;
            *(float4*)(out + (size_t)m * N + nB) = r1;
        } else {
            ushort* ob = (ushort*)out;
            int b = m >> 11;            // m / T_SZ
            int t = m & 2047;           // m % T_SZ
#pragma unroll
            for (int j = 0; j < 8; ++j) {
                int n = n0 + ((j < 4) ? (tx * 4 + j) : (64 + tx * 4 + (j - 4)));
                float val = acc[i][j] + bias[n];
                int mat  = n / EMBEDC;          // 0=q 1=k 2=v
                int c    = n - mat * EMBEDC;
                int head = c % NHEADS;          // inner factor!
                int hd   = c / NHEADS;
                size_t bh = (size_t)(b * NHEADS + head);
                if (mat == 0)
                    ob[(bh * T_SZ + t) * HEADD + hd] = f2bf(val * 0.125f);
                else if (mat == 1)
                    ob[QKV_PER + (bh * T_SZ + t) * HEADD + hd] = f2bf(val);
                else
                    ob[2 * (size_t)QKV_PER + (bh * HEADD + hd) * T_SZ + t] = f2bf(val);
            }
        }
    }
}

// ---------------------------------------------------------------------------
// bf16 MFMA flash attention. Grid: (T/64, B*NHEADS), 256 threads = 4 waves.
// Wave w owns q rows [16w,16w+16). Per kv-tile of 64:
//   S^T = mfma(A=K, B=Q^T)  -> lane owns one q col (l&15), 16 kv rows
//   online softmax per-lane scalar (shfl_xor 16/32 across the 4 lane-groups)
//   P^T redistributed to B-frags via 16 __shfl; O^T += mfma(A=V^T, B=P^T)
// K and V^T tiles in LDS, XOR-swizzled: 16B chunk c -> c ^ (row&7) (G4 fix).
// MFMA layouts (16x16x32): A[row=l&15][k=8*(l>>4)+j]; B[k=8*(l>>4)+j][col=l&15];
// C/D[row=(l>>4)*4+r][col=l&15] (guide §3, m89/m91-verified).
// ---------------------------------------------------------------------------
__global__ __launch_bounds__(256) void attn_mfma_k(
    const ushort* __restrict__ Qb, const ushort* __restrict__ Kb,
    const ushort* __restrict__ Vtb, float* __restrict__ Out)
{
    __shared__ ushort Ks[64 * 64];   // [kv][d]  swizzled
    __shared__ ushort Vs[64 * 64];   // [d][kv]  swizzled (V^T)

    const int qb = blockIdx.x;
    const int bh = blockIdx.y;
    const int bb = bh / NHEADS, head = bh % NHEADS;
    const int tid = threadIdx.x;
    const int w = tid >> 6, l = tid & 63;
    const int g = l >> 4, r16 = l & 15;
    const int q0 = qb * 64;
    const size_t baseQK = (size_t)bh * T_SZ * HEADD;
    const size_t baseVt = (size_t)bh * HEADD * T_SZ;

    // Q B-frags (q pre-scaled by 0.125 in K1): B[k=d][col=q], q = q0+16w+r16
    bf16x8 qf[2];
    {
        const ushort* qp = Qb + baseQK + (size_t)(q0 + 16 * w + r16) * HEADD + g * 8;
        qf[0] = *(const bf16x8*)(qp);
        qf[1] = *(const bf16x8*)(qp + 32);
    }

    f32x4 o[4];                       // O^T acc: o[dc][r] = O^T[dc*16+4g+r][q]
#pragma unroll
    for (int dc = 0; dc < 4; ++dc) o[dc] = (f32x4){0.f, 0.f, 0.f, 0.f};
    float mR = -1e30f, lR = 0.f;

    for (int kt = 0; kt <= qb; ++kt) {
        const int k0 = kt * 64;
        __syncthreads();              // prior iter's LDS readers done
#pragma unroll
        for (int u = 0; u < 2; ++u) {
            int f = tid + 256 * u;
            int row = f >> 3, c8 = f & 7;
            int dst = ((c8 ^ (row & 7)) * 8);
            *(bf16x8*)&Ks[row * 64 + dst] =
                *(const bf16x8*)(Kb + baseQK + (size_t)(k0 + row) * HEADD + c8 * 8);
            *(bf16x8*)&Vs[row * 64 + dst] =
                *(const bf16x8*)(Vtb + baseVt + (size_t)row * T_SZ + k0 + c8 * 8);
        }
        __syncthreads();

        // S^T[kv][q]: 4 kv-subtiles x (2 MFMAs over d)
        f32x4 st[4];
#pragma unroll
        for (int kc = 0; kc < 4; ++kc) {
            int row = kc * 16 + r16;
            const ushort* kr = &Ks[row * 64];
            bf16x8 a0 = *(const bf16x8*)(kr + ((g     ) ^ (row & 7)) * 8);
            bf16x8 a1 = *(const bf16x8*)(kr + ((g + 4 ) ^ (row & 7)) * 8);
            f32x4 c = (f32x4){0.f, 0.f, 0.f, 0.f};
            c = __builtin_amdgcn_mfma_f32_16x16x32_bf16(a0, qf[0], c, 0, 0, 0);
            c = __builtin_amdgcn_mfma_f32_16x16x32_bf16(a1, qf[1], c, 0, 0, 0);
            st[kc] = c;
        }

        if (kt == qb) {               // causal mask, diagonal tile only
            const int qloc = 16 * w + r16;
#pragma unroll
            for (int kc = 0; kc < 4; ++kc)
#pragma unroll
                for (int r = 0; r < 4; ++r)
                    if (kc * 16 + 4 * g + r > qloc) st[kc][r] = -1e30f;
        }

        // online softmax: lane owns q = r16 (replicated over the 4 groups)
        float pm = -1e30f;
#pragma unroll
        for (int kc = 0; kc < 4; ++kc)
#pragma unroll
            for (int r = 0; r < 4; ++r) pm = fmaxf(pm, st[kc][r]);
        pm = fmaxf(pm, __shfl_xor(pm, 16));
        pm = fmaxf(pm, __shfl_xor(pm, 32));
        float mNew = fmaxf(mR, pm);
        float sc = __expf(mR - mNew);
        float p[16];
        float rs = 0.f;
#pragma unroll
        for (int kc = 0; kc < 4; ++kc)
#pragma unroll
            for (int r = 0; r < 4; ++r) {
                float e = __expf(st[kc][r] - mNew);
                p[kc * 4 + r] = e;
                rs += e;
            }
        rs += __shfl_xor(rs, 16);
        rs += __shfl_xor(rs, 32);
        lR = lR * sc + rs;
        mR = mNew;
#pragma unroll
        for (int dc = 0; dc < 4; ++dc) o[dc] *= sc;

        // pack P^T to bf16 pairs: pk[kc][h] = (p[4kc+2h], p[4kc+2h+1])
        uint pk[4][2];
#pragma unroll
        for (int kc = 0; kc < 4; ++kc) {
            pk[kc][0] = (uint)f2bf(p[kc * 4 + 0]) | ((uint)f2bf(p[kc * 4 + 1]) << 16);
            pk[kc][1] = (uint)f2bf(p[kc * 4 + 2]) | ((uint)f2bf(p[kc * 4 + 3]) << 16);
        }

        // redistribute P^T into B-frag layout: B[k=8g+j][col=q]
        // dest group g wants subtile st = 2s+(g>>1), rows 8(g&1)..+7
        const int srcLo = ((g & 1) << 5) | r16;
        const int srcHi = srcLo + 16;
        const bool hiSel = (g >> 1) != 0;
        bf16x8 pb[2];
#pragma unroll
        for (int s = 0; s < 2; ++s) {
            uint A0 = (uint)__shfl((int)pk[2 * s][0],     srcLo);
            uint A1 = (uint)__shfl((int)pk[2 * s][1],     srcLo);
            uint B0 = (uint)__shfl((int)pk[2 * s + 1][0], srcLo);
            uint B1 = (uint)__shfl((int)pk[2 * s + 1][1], srcLo);
            uint A2 = (uint)__shfl((int)pk[2 * s][0],     srcHi);
            uint A3 = (uint)__shfl((int)pk[2 * s][1],     srcHi);
            uint B2 = (uint)__shfl((int)pk[2 * s + 1][0], srcHi);
            uint B3 = (uint)__shfl((int)pk[2 * s + 1][1], srcHi);
            union { uint u[4]; bf16x8 v; } t;
            t.u[0] = hiSel ? B0 : A0;
            t.u[1] = hiSel ? B1 : A1;
            t.u[2] = hiSel ? B2 : A2;
            t.u[3] = hiSel ? B3 : A3;
            pb[s] = t.v;
        }

        // O^T += V^T · P^T
#pragma unroll
        for (int dc = 0; dc < 4; ++dc) {
            int row = dc * 16 + r16;
            const ushort* vr = &Vs[row * 64];
            bf16x8 v0 = *(const bf16x8*)(vr + ((g     ) ^ (row & 7)) * 8);
            bf16x8 v1 = *(const bf16x8*)(vr + ((g + 4 ) ^ (row & 7)) * 8);
            o[dc] = __builtin_amdgcn_mfma_f32_16x16x32_bf16(v0, pb[0], o[dc], 0, 0, 0);
            o[dc] = __builtin_amdgcn_mfma_f32_16x16x32_bf16(v1, pb[1], o[dc], 0, 0, 0);
        }
    }

    // epilogue: att[b][t=q][head*64 + d], d = dc*16+4g+r, q = q0+16w+r16
    const float inv = 1.f / lR;
    const int q = q0 + 16 * w + r16;
    float* orow = Out + ((size_t)(bb * T_SZ + q)) * EMBEDC + head * HEADD;
#pragma unroll
    for (int dc = 0; dc < 4; ++dc)
#pragma unroll
        for (int r = 0; r < 4; ++r)
            orow[dc * 16 + 4 * g + r] = o[dc][r] * inv;
}

// ---------------------------------------------------------------------------
extern "C" void kernel_launch(void* const* d_in, const int* in_sizes, int n_in,
                              void* d_out, int out_size, void* d_ws, size_t ws_size,
                              hipStream_t stream)
{
    const float* x      = (const float*)d_in[0];   // [2,2048,768]
    const float* w_attn = (const float*)d_in[1];   // [768,2304]
    const float* b_attn = (const float*)d_in[2];   // [2304]
    const float* w_proj = (const float*)d_in[3];   // [768,768]
    const float* b_proj = (const float*)d_in[4];   // [768]
    float* out = (float*)d_out;                    // [2,2048,768] f32

    // Workspace: q,k (bf16 [bh][t][hd]), vT (bf16 [bh][hd][t]), att (f32)
    ushort* qw  = (ushort*)d_ws;
    float*  att = (float*)((char*)d_ws + (size_t)3 * QKV_PER * sizeof(ushort));

    // K1: qkv = x @ w_attn + b_attn  -> bf16 q/k/vT workspace
    gemm_f32_k<1><<<dim3(2304 / 128, 4096 / 128), 256, 0, stream>>>(
        x, w_attn, b_attn, (float*)qw, NB * T_SZ, 3 * EMBEDC, EMBEDC);

    // K2: bf16 MFMA causal flash attention
    attn_mfma_k<<<dim3(T_SZ / 64, NB * NHEADS), 256, 0, stream>>>(
        qw, qw + QKV_PER, qw + 2 * (size_t)QKV_PER, att);

    // K3: out = att @ w_proj + b_proj (f32)
    gemm_f32_k<0><<<dim3(768 / 128, 4096 / 128), 256, 0, stream>>>(
        att, w_proj, b_proj, out, NB * T_SZ, EMBEDC, EMBEDC);
}

// Round 3
// 164.476 us; speedup vs baseline: 5.6479x; 2.3000x over previous
//
#include <hip/hip_runtime.h>
#include <hip/hip_bf16.h>
#include <math.h>

// Problem constants (GPT2Attention: B=2, T=2048, EMBED=768, 12 heads, head=64)
#define NB      2
#define T_SZ    2048
#define EMBEDC  768
#define NHEADS  12
#define HEADD   64
#define QKV_PER (NB * NHEADS * T_SZ * HEADD)   // 3,145,728 elems per q/k/v

typedef __bf16 bf16x8 __attribute__((ext_vector_type(8)));
typedef float  f32x4  __attribute__((ext_vector_type(4)));

__device__ inline ushort f2bf(float x) {
    union { float f; uint u; } v; v.f = x;
    uint r = v.u + 0x7fffu + ((v.u >> 16) & 1u);   // RNE
    return (ushort)(r >> 16);
}

__device__ inline void gload16(const ushort* g, ushort* l) {
    __builtin_amdgcn_global_load_lds(
        (const __attribute__((address_space(1))) unsigned int*)g,
        (__attribute__((address_space(3))) unsigned int*)l, 16, 0, 0);
}

// ---------------------------------------------------------------------------
// f32 -> bf16 elementwise cast (8 elems/thread)
// ---------------------------------------------------------------------------
__global__ __launch_bounds__(256) void cast_k(const float* __restrict__ in,
                                              ushort* __restrict__ out, int n)
{
    int i = (blockIdx.x * 256 + threadIdx.x) * 8;
    if (i >= n) return;
    float4 a = *(const float4*)(in + i);
    float4 b = *(const float4*)(in + i + 4);
    union { ushort u[8]; int4 v; } p;
    p.u[0] = f2bf(a.x); p.u[1] = f2bf(a.y); p.u[2] = f2bf(a.z); p.u[3] = f2bf(a.w);
    p.u[4] = f2bf(b.x); p.u[5] = f2bf(b.y); p.u[6] = f2bf(b.z); p.u[7] = f2bf(b.w);
    *(int4*)(out + i) = p.v;
}

// ---------------------------------------------------------------------------
// Transpose-cast: in[R][C] f32 -> out[C][R] bf16. 32x32 LDS tile (pad +1).
// ---------------------------------------------------------------------------
__global__ __launch_bounds__(256) void tcast_k(const float* __restrict__ in,
                                               ushort* __restrict__ out,
                                               int R, int C)
{
    __shared__ float t[32][33];
    const int c0 = blockIdx.x * 32, r0 = blockIdx.y * 32;
    const int tx = threadIdx.x & 31, ty = threadIdx.x >> 5;
#pragma unroll
    for (int u = 0; u < 4; ++u)
        t[ty + 8 * u][tx] = in[(size_t)(r0 + ty + 8 * u) * C + c0 + tx];
    __syncthreads();
#pragma unroll
    for (int u = 0; u < 4; ++u)
        out[(size_t)(c0 + ty + 8 * u) * R + r0 + tx] = f2bf(t[tx][ty + 8 * u]);
}

// ---------------------------------------------------------------------------
// bf16 MFMA GEMM: C[M][N] = A[M][K] @ Bt[N][K]^T (+bias). 128x128 tile,
// BK=32, 256 threads = 4 waves (2x2), each wave 64x64 = 4x4 16x16x32 frags.
// Staging: global_load_lds 16B/lane into LINEAR LDS [row][32k]; the 16B
// chunk index is pre-swizzled on the GLOBAL source (c ^= row&3) and the
// same XOR is applied on ds_read_b128 (rule 21: both-sides-or-neither).
// MODE 0: f32 store out[m*N+n] = acc + bias[n]
// MODE 1: QKV scatter -> bf16 q [bh][t][hd] (scaled 0.125), k [bh][t][hd],
//         vT [bh][hd][t]  (head = c%12 inner factor per reference reshape)
// ---------------------------------------------------------------------------
template <int MODE>
__global__ __launch_bounds__(256) void gemm_bf16_k(
    const ushort* __restrict__ A, const ushort* __restrict__ Bt,
    const float* __restrict__ bias, void* __restrict__ outp,
    int M, int N, int K)
{
    __shared__ ushort As[128 * 32];
    __shared__ ushort Bs[128 * 32];

    const int tid = threadIdx.x;
    const int w = tid >> 6, l = tid & 63;
    const int g = l >> 4, r16 = l & 15;
    const int wr = w >> 1, wc = w & 1;
    const int m0 = blockIdx.y * 128, n0 = blockIdx.x * 128;

    // staging addresses: lane stages 16B at tile-row 32w+16u+(l>>2),
    // source chunk swizzled by row&3 (= (l>>2)&3 since 32w+16u = 0 mod 4)
    const int srow = l >> 2;
    const int sc = ((l & 3) ^ (srow & 3)) * 8;     // element offset in row
    const ushort* gA0 = A + (size_t)(m0 + 32 * w + srow) * K + sc;
    const ushort* gA1 = gA0 + (size_t)16 * K;
    const ushort* gB0 = Bt + (size_t)(n0 + 32 * w + srow) * K + sc;
    const ushort* gB1 = gB0 + (size_t)16 * K;
    ushort* lA0 = &As[(32 * w) * 32];
    ushort* lA1 = &As[(32 * w + 16) * 32];
    ushort* lB0 = &Bs[(32 * w) * 32];
    ushort* lB1 = &Bs[(32 * w + 16) * 32];

    f32x4 acc[4][4];
#pragma unroll
    for (int i = 0; i < 4; ++i)
#pragma unroll
        for (int j = 0; j < 4; ++j) acc[i][j] = (f32x4){0.f, 0.f, 0.f, 0.f};

    const int rck = (r16 & 3);                     // read-side XOR key

    for (int k0 = 0; k0 < K; k0 += 32) {
        gload16(gA0 + k0, lA0);
        gload16(gA1 + k0, lA1);
        gload16(gB0 + k0, lB0);
        gload16(gB1 + k0, lB1);
        __syncthreads();                           // drains vmcnt before reads

        bf16x8 af[4], bfr[4];
#pragma unroll
        for (int ms = 0; ms < 4; ++ms) {
            int row = 64 * wr + 16 * ms + r16;     // row&3 == r16&3
            af[ms] = *(const bf16x8*)&As[row * 32 + ((g ^ rck) * 8)];
        }
#pragma unroll
        for (int ns = 0; ns < 4; ++ns) {
            int row = 64 * wc + 16 * ns + r16;
            bfr[ns] = *(const bf16x8*)&Bs[row * 32 + ((g ^ rck) * 8)];
        }
#pragma unroll
        for (int ms = 0; ms < 4; ++ms)
#pragma unroll
            for (int ns = 0; ns < 4; ++ns)
                acc[ms][ns] = __builtin_amdgcn_mfma_f32_16x16x32_bf16(
                    af[ms], bfr[ns], acc[ms][ns], 0, 0, 0);
        __syncthreads();                           // readers done before restage
    }

    // Epilogue. D[row=(l>>4)*4+r][col=l&15]: m = m0+64wr+16ms+4g+r, n = ...+r16
#pragma unroll
    for (int ns = 0; ns < 4; ++ns) {
        const int n = n0 + 64 * wc + 16 * ns + r16;
        const float bv = bias[n];
        if (MODE == 0) {
            float* out = (float*)outp;
#pragma unroll
            for (int ms = 0; ms < 4; ++ms) {
                const int mb = m0 + 64 * wr + 16 * ms + 4 * g;
#pragma unroll
                for (int r = 0; r < 4; ++r)
                    out[(size_t)(mb + r) * N + n] = acc[ms][ns][r] + bv;
            }
        } else {
            ushort* ob = (ushort*)outp;
            const int mat  = n / EMBEDC;           // 0=q 1=k 2=v
            const int c    = n - mat * EMBEDC;
            const int head = c % NHEADS;           // inner factor!
            const int hd   = c / NHEADS;
#pragma unroll
            for (int ms = 0; ms < 4; ++ms) {
                const int mb = m0 + 64 * wr + 16 * ms + 4 * g;
#pragma unroll
                for (int r = 0; r < 4; ++r) {
                    const int m = mb + r;
                    const int b = m >> 11, t = m & 2047;
                    const size_t bh = (size_t)(b * NHEADS + head);
                    const float val = acc[ms][ns][r] + bv;
                    if (mat == 0)
                        ob[(bh * T_SZ + t) * HEADD + hd] = f2bf(val * 0.125f);
                    else if (mat == 1)
                        ob[QKV_PER + (bh * T_SZ + t) * HEADD + hd] = f2bf(val);
                    else
                        ob[2 * (size_t)QKV_PER + (bh * HEADD + hd) * T_SZ + t] =
                            f2bf(val);
                }
            }
        }
    }
}

// ---------------------------------------------------------------------------
// bf16 MFMA flash attention (unchanged from round 2 except bf16 output).
// Grid: (T/64, B*NHEADS), 256 threads = 4 waves; wave w owns q rows 16w..+16.
// S^T = mfma(A=K, B=Q^T); per-lane online softmax; P^T via 16 __shfl;
// O^T += mfma(A=V^T, B=P^T). K/V^T LDS tiles XOR-swizzled (chunk ^= row&7).
// ---------------------------------------------------------------------------
__global__ __launch_bounds__(256) void attn_mfma_k(
    const ushort* __restrict__ Qb, const ushort* __restrict__ Kb,
    const ushort* __restrict__ Vtb, ushort* __restrict__ Out)
{
    __shared__ ushort Ks[64 * 64];   // [kv][d]  swizzled
    __shared__ ushort Vs[64 * 64];   // [d][kv]  swizzled (V^T)

    const int qb = blockIdx.x;
    const int bh = blockIdx.y;
    const int bb = bh / NHEADS, head = bh % NHEADS;
    const int tid = threadIdx.x;
    const int w = tid >> 6, l = tid & 63;
    const int g = l >> 4, r16 = l & 15;
    const int q0 = qb * 64;
    const size_t baseQK = (size_t)bh * T_SZ * HEADD;
    const size_t baseVt = (size_t)bh * HEADD * T_SZ;

    bf16x8 qf[2];
    {
        const ushort* qp = Qb + baseQK + (size_t)(q0 + 16 * w + r16) * HEADD + g * 8;
        qf[0] = *(const bf16x8*)(qp);
        qf[1] = *(const bf16x8*)(qp + 32);
    }

    f32x4 o[4];
#pragma unroll
    for (int dc = 0; dc < 4; ++dc) o[dc] = (f32x4){0.f, 0.f, 0.f, 0.f};
    float mR = -1e30f, lR = 0.f;

    for (int kt = 0; kt <= qb; ++kt) {
        const int k0 = kt * 64;
        __syncthreads();
#pragma unroll
        for (int u = 0; u < 2; ++u) {
            int f = tid + 256 * u;
            int row = f >> 3, c8 = f & 7;
            int dst = ((c8 ^ (row & 7)) * 8);
            *(bf16x8*)&Ks[row * 64 + dst] =
                *(const bf16x8*)(Kb + baseQK + (size_t)(k0 + row) * HEADD + c8 * 8);
            *(bf16x8*)&Vs[row * 64 + dst] =
                *(const bf16x8*)(Vtb + baseVt + (size_t)row * T_SZ + k0 + c8 * 8);
        }
        __syncthreads();

        f32x4 st[4];
#pragma unroll
        for (int kc = 0; kc < 4; ++kc) {
            int row = kc * 16 + r16;
            const ushort* kr = &Ks[row * 64];
            bf16x8 a0 = *(const bf16x8*)(kr + ((g    ) ^ (row & 7)) * 8);
            bf16x8 a1 = *(const bf16x8*)(kr + ((g + 4) ^ (row & 7)) * 8);
            f32x4 c = (f32x4){0.f, 0.f, 0.f, 0.f};
            c = __builtin_amdgcn_mfma_f32_16x16x32_bf16(a0, qf[0], c, 0, 0, 0);
            c = __builtin_amdgcn_mfma_f32_16x16x32_bf16(a1, qf[1], c, 0, 0, 0);
            st[kc] = c;
        }

        if (kt == qb) {
            const int qloc = 16 * w + r16;
#pragma unroll
            for (int kc = 0; kc < 4; ++kc)
#pragma unroll
                for (int r = 0; r < 4; ++r)
                    if (kc * 16 + 4 * g + r > qloc) st[kc][r] = -1e30f;
        }

        float pm = -1e30f;
#pragma unroll
        for (int kc = 0; kc < 4; ++kc)
#pragma unroll
            for (int r = 0; r < 4; ++r) pm = fmaxf(pm, st[kc][r]);
        pm = fmaxf(pm, __shfl_xor(pm, 16));
        pm = fmaxf(pm, __shfl_xor(pm, 32));
        float mNew = fmaxf(mR, pm);
        float sc = __expf(mR - mNew);
        float p[16];
        float rs = 0.f;
#pragma unroll
        for (int kc = 0; kc < 4; ++kc)
#pragma unroll
            for (int r = 0; r < 4; ++r) {
                float e = __expf(st[kc][r] - mNew);
                p[kc * 4 + r] = e;
                rs += e;
            }
        rs += __shfl_xor(rs, 16);
        rs += __shfl_xor(rs, 32);
        lR = lR * sc + rs;
        mR = mNew;
#pragma unroll
        for (int dc = 0; dc < 4; ++dc) o[dc] *= sc;

        uint pk[4][2];
#pragma unroll
        for (int kc = 0; kc < 4; ++kc) {
            pk[kc][0] = (uint)f2bf(p[kc * 4 + 0]) | ((uint)f2bf(p[kc * 4 + 1]) << 16);
            pk[kc][1] = (uint)f2bf(p[kc * 4 + 2]) | ((uint)f2bf(p[kc * 4 + 3]) << 16);
        }

        const int srcLo = ((g & 1) << 5) | r16;
        const int srcHi = srcLo + 16;
        const bool hiSel = (g >> 1) != 0;
        bf16x8 pb[2];
#pragma unroll
        for (int s = 0; s < 2; ++s) {
            uint A0 = (uint)__shfl((int)pk[2 * s][0],     srcLo);
            uint A1 = (uint)__shfl((int)pk[2 * s][1],     srcLo);
            uint B0 = (uint)__shfl((int)pk[2 * s + 1][0], srcLo);
            uint B1 = (uint)__shfl((int)pk[2 * s + 1][1], srcLo);
            uint A2 = (uint)__shfl((int)pk[2 * s][0],     srcHi);
            uint A3 = (uint)__shfl((int)pk[2 * s][1],     srcHi);
            uint B2 = (uint)__shfl((int)pk[2 * s + 1][0], srcHi);
            uint B3 = (uint)__shfl((int)pk[2 * s + 1][1], srcHi);
            union { uint u[4]; bf16x8 v; } t;
            t.u[0] = hiSel ? B0 : A0;
            t.u[1] = hiSel ? B1 : A1;
            t.u[2] = hiSel ? B2 : A2;
            t.u[3] = hiSel ? B3 : A3;
            pb[s] = t.v;
        }

#pragma unroll
        for (int dc = 0; dc < 4; ++dc) {
            int row = dc * 16 + r16;
            const ushort* vr = &Vs[row * 64];
            bf16x8 v0 = *(const bf16x8*)(vr + ((g    ) ^ (row & 7)) * 8);
            bf16x8 v1 = *(const bf16x8*)(vr + ((g + 4) ^ (row & 7)) * 8);
            o[dc] = __builtin_amdgcn_mfma_f32_16x16x32_bf16(v0, pb[0], o[dc], 0, 0, 0);
            o[dc] = __builtin_amdgcn_mfma_f32_16x16x32_bf16(v1, pb[1], o[dc], 0, 0, 0);
        }
    }

    // epilogue: att bf16 [b][t=q][head*64 + d]
    const float inv = 1.f / lR;
    const int q = q0 + 16 * w + r16;
    ushort* orow = Out + ((size_t)(bb * T_SZ + q)) * EMBEDC + head * HEADD;
#pragma unroll
    for (int dc = 0; dc < 4; ++dc)
#pragma unroll
        for (int r = 0; r < 4; ++r)
            orow[dc * 16 + 4 * g + r] = f2bf(o[dc][r] * inv);
}

// ---------------------------------------------------------------------------
extern "C" void kernel_launch(void* const* d_in, const int* in_sizes, int n_in,
                              void* d_out, int out_size, void* d_ws, size_t ws_size,
                              hipStream_t stream)
{
    const float* x      = (const float*)d_in[0];   // [2,2048,768]
    const float* w_attn = (const float*)d_in[1];   // [768,2304]
    const float* b_attn = (const float*)d_in[2];   // [2304]
    const float* w_proj = (const float*)d_in[3];   // [768,768]
    const float* b_proj = (const float*)d_in[4];   // [768]
    float* out = (float*)d_out;                    // [2,2048,768] f32

    // Workspace (ushort units): q,k,vT | att | x_bf | w_attnT | w_projT
    ushort* qw   = (ushort*)d_ws;
    ushort* attb = qw + (size_t)3 * QKV_PER;
    ushort* xb   = attb + QKV_PER;
    ushort* waT  = xb + QKV_PER;                   // x has QKV_PER elems
    ushort* wpT  = waT + (size_t)EMBEDC * 3 * EMBEDC;

    // casts
    cast_k<<<QKV_PER / (256 * 8), 256, 0, stream>>>(x, xb, QKV_PER);
    tcast_k<<<dim3(3 * EMBEDC / 32, EMBEDC / 32), 256, 0, stream>>>(
        w_attn, waT, EMBEDC, 3 * EMBEDC);
    tcast_k<<<dim3(EMBEDC / 32, EMBEDC / 32), 256, 0, stream>>>(
        w_proj, wpT, EMBEDC, EMBEDC);

    // K1: qkv = x @ w_attn + b_attn -> bf16 q/k/vT (MFMA)
    gemm_bf16_k<1><<<dim3(2304 / 128, 4096 / 128), 256, 0, stream>>>(
        xb, waT, b_attn, qw, NB * T_SZ, 3 * EMBEDC, EMBEDC);

    // K2: bf16 MFMA causal flash attention -> bf16 att
    attn_mfma_k<<<dim3(T_SZ / 64, NB * NHEADS), 256, 0, stream>>>(
        qw, qw + QKV_PER, qw + 2 * (size_t)QKV_PER, attb);

    // K3: out = att @ w_proj + b_proj (f32 out, MFMA)
    gemm_bf16_k<0><<<dim3(768 / 128, 4096 / 128), 256, 0, stream>>>(
        attb, wpT, b_proj, out, NB * T_SZ, EMBEDC, EMBEDC);
}

// Round 4
// 137.962 us; speedup vs baseline: 6.7333x; 1.1922x over previous
//
#include <hip/hip_runtime.h>
#include <hip/hip_bf16.h>
#include <math.h>

// Problem constants (GPT2Attention: B=2, T=2048, EMBED=768, 12 heads, head=64)
#define NB      2
#define T_SZ    2048
#define EMBEDC  768
#define NHEADS  12
#define HEADD   64
#define QKV_PER (NB * NHEADS * T_SZ * HEADD)   // 3,145,728 elems per q/k/v
// q pre-scale: HEAD^-0.5 * log2(e), so softmax can use exp2 directly
#define QSCALE  0.18033688011112042f

typedef __bf16 bf16x8 __attribute__((ext_vector_type(8)));
typedef float  f32x4  __attribute__((ext_vector_type(4)));

__device__ inline ushort f2bf(float x) {
    union { float f; uint u; } v; v.f = x;
    uint r = v.u + 0x7fffu + ((v.u >> 16) & 1u);   // RNE
    return (ushort)(r >> 16);
}

__device__ inline void gload16(const ushort* g, ushort* l) {
    __builtin_amdgcn_global_load_lds(
        (const __attribute__((address_space(1))) unsigned int*)g,
        (__attribute__((address_space(3))) unsigned int*)l, 16, 0, 0);
}

// ---------------------------------------------------------------------------
// f32 -> bf16 elementwise cast (8 elems/thread)
// ---------------------------------------------------------------------------
__global__ __launch_bounds__(256) void cast_k(const float* __restrict__ in,
                                              ushort* __restrict__ out, int n)
{
    int i = (blockIdx.x * 256 + threadIdx.x) * 8;
    if (i >= n) return;
    float4 a = *(const float4*)(in + i);
    float4 b = *(const float4*)(in + i + 4);
    union { ushort u[8]; int4 v; } p;
    p.u[0] = f2bf(a.x); p.u[1] = f2bf(a.y); p.u[2] = f2bf(a.z); p.u[3] = f2bf(a.w);
    p.u[4] = f2bf(b.x); p.u[5] = f2bf(b.y); p.u[6] = f2bf(b.z); p.u[7] = f2bf(b.w);
    *(int4*)(out + i) = p.v;
}

// ---------------------------------------------------------------------------
// Transpose-cast: in[R][C] f32 -> out[C'][R] bf16, 32x32 LDS tile.
// PERM=1 relocates output row n -> mat*768 + (c%12)*64 + c/12 (c = n%768),
// so GEMM output columns come out in [mat][head][hd] order (coalesced QKV
// epilogue). Row relocation only: write coalescing along k unchanged.
// ---------------------------------------------------------------------------
template <int PERM>
__global__ __launch_bounds__(256) void tcast_k(const float* __restrict__ in,
                                               ushort* __restrict__ out,
                                               int R, int C)
{
    __shared__ float t[32][33];
    const int c0 = blockIdx.x * 32, r0 = blockIdx.y * 32;
    const int tx = threadIdx.x & 31, ty = threadIdx.x >> 5;
#pragma unroll
    for (int u = 0; u < 4; ++u)
        t[ty + 8 * u][tx] = in[(size_t)(r0 + ty + 8 * u) * C + c0 + tx];
    __syncthreads();
#pragma unroll
    for (int u = 0; u < 4; ++u) {
        int n = c0 + ty + 8 * u;
        int orow = n;
        if (PERM) {
            int mat = n / EMBEDC, cc = n % EMBEDC;
            orow = mat * EMBEDC + (cc % NHEADS) * HEADD + cc / NHEADS;
        }
        out[(size_t)orow * R + r0 + tx] = f2bf(t[tx][ty + 8 * u]);
    }
}

// ---------------------------------------------------------------------------
// V transpose: in [bh][t][hd] bf16 -> out [bh][hd][t] bf16. 64x64 LDS tile.
// ---------------------------------------------------------------------------
__global__ __launch_bounds__(256) void vt_k(const ushort* __restrict__ in,
                                            ushort* __restrict__ out)
{
    __shared__ ushort tile[64][66];   // pad 2: column reads ~2-way (free, m136)
    const int bh = blockIdx.y;
    const int t0 = blockIdx.x * 64;
    const int tid = threadIdx.x;
#pragma unroll
    for (int u = 0; u < 2; ++u) {
        int s = tid + 256 * u;
        int r = s >> 3, c8 = s & 7;
        *(bf16x8*)&tile[r][c8 * 8] =
            *(const bf16x8*)(in + ((size_t)bh * T_SZ + t0 + r) * HEADD + c8 * 8);
    }
    __syncthreads();
#pragma unroll
    for (int u = 0; u < 2; ++u) {
        int s = tid + 256 * u;
        int hd = s >> 3, tt = s & 7;
        union { ushort v[8]; int4 q; } pk;
#pragma unroll
        for (int j = 0; j < 8; ++j) pk.v[j] = tile[tt * 8 + j][hd];
        *(int4*)(out + ((size_t)bh * HEADD + hd) * T_SZ + t0 + tt * 8) = pk.q;
    }
}

// ---------------------------------------------------------------------------
// bf16 MFMA GEMM: C[M][N] = A[M][K] @ Bt[N][K]^T (+bias). 128x128 tile,
// BK=32, 256 threads = 4 waves (2x2), each wave 64x64 = 4x4 16x16x32 frags.
// global_load_lds 16B into linear LDS, source chunk pre-swizzled (c ^= row&3)
// with matching XOR on ds_read_b128 (rule 21).
// MODE 0: f32 store out[m*N+n] = acc + bias[n]
// MODE 1: columns arrive PERMUTED as n' = mat*768 + head*64 + hd (tcast<1>);
//         writes q (scaled QSCALE) / k / v all to [mat][bh][t][hd], 16 lanes
//         = 32B contiguous sectors. bias indexed via original n.
// ---------------------------------------------------------------------------
template <int MODE>
__global__ __launch_bounds__(256) void gemm_bf16_k(
    const ushort* __restrict__ A, const ushort* __restrict__ Bt,
    const float* __restrict__ bias, void* __restrict__ outp,
    int M, int N, int K)
{
    __shared__ ushort As[128 * 32];
    __shared__ ushort Bs[128 * 32];

    const int tid = threadIdx.x;
    const int w = tid >> 6, l = tid & 63;
    const int g = l >> 4, r16 = l & 15;
    const int wr = w >> 1, wc = w & 1;
    const int m0 = blockIdx.y * 128, n0 = blockIdx.x * 128;

    const int srow = l >> 2;
    const int sc = ((l & 3) ^ (srow & 3)) * 8;
    const ushort* gA0 = A + (size_t)(m0 + 32 * w + srow) * K + sc;
    const ushort* gA1 = gA0 + (size_t)16 * K;
    const ushort* gB0 = Bt + (size_t)(n0 + 32 * w + srow) * K + sc;
    const ushort* gB1 = gB0 + (size_t)16 * K;
    ushort* lA0 = &As[(32 * w) * 32];
    ushort* lA1 = &As[(32 * w + 16) * 32];
    ushort* lB0 = &Bs[(32 * w) * 32];
    ushort* lB1 = &Bs[(32 * w + 16) * 32];

    f32x4 acc[4][4];
#pragma unroll
    for (int i = 0; i < 4; ++i)
#pragma unroll
        for (int j = 0; j < 4; ++j) acc[i][j] = (f32x4){0.f, 0.f, 0.f, 0.f};

    const int rck = (r16 & 3);

    for (int k0 = 0; k0 < K; k0 += 32) {
        gload16(gA0 + k0, lA0);
        gload16(gA1 + k0, lA1);
        gload16(gB0 + k0, lB0);
        gload16(gB1 + k0, lB1);
        __syncthreads();

        bf16x8 af[4], bfr[4];
#pragma unroll
        for (int ms = 0; ms < 4; ++ms) {
            int row = 64 * wr + 16 * ms + r16;
            af[ms] = *(const bf16x8*)&As[row * 32 + ((g ^ rck) * 8)];
        }
#pragma unroll
        for (int ns = 0; ns < 4; ++ns) {
            int row = 64 * wc + 16 * ns + r16;
            bfr[ns] = *(const bf16x8*)&Bs[row * 32 + ((g ^ rck) * 8)];
        }
        __builtin_amdgcn_s_setprio(1);
#pragma unroll
        for (int ms = 0; ms < 4; ++ms)
#pragma unroll
            for (int ns = 0; ns < 4; ++ns)
                acc[ms][ns] = __builtin_amdgcn_mfma_f32_16x16x32_bf16(
                    af[ms], bfr[ns], acc[ms][ns], 0, 0, 0);
        __builtin_amdgcn_s_setprio(0);
        __syncthreads();
    }

#pragma unroll
    for (int ns = 0; ns < 4; ++ns) {
        const int n = n0 + 64 * wc + 16 * ns + r16;
        if (MODE == 0) {
            float* out = (float*)outp;
            const float bv = bias[n];
#pragma unroll
            for (int ms = 0; ms < 4; ++ms) {
                const int mb = m0 + 64 * wr + 16 * ms + 4 * g;
#pragma unroll
                for (int r = 0; r < 4; ++r)
                    out[(size_t)(mb + r) * N + n] = acc[ms][ns][r] + bv;
            }
        } else {
            ushort* ob = (ushort*)outp;
            const int mat  = n / EMBEDC;         // n is the PERMUTED column n'
            const int c    = n - mat * EMBEDC;
            const int head = c >> 6;
            const int hd   = c & 63;
            const float bv = bias[mat * EMBEDC + hd * NHEADS + head];
            const float qs = (mat == 0) ? QSCALE : 1.f;
#pragma unroll
            for (int ms = 0; ms < 4; ++ms) {
                const int mb = m0 + 64 * wr + 16 * ms + 4 * g;
#pragma unroll
                for (int r = 0; r < 4; ++r) {
                    const int m = mb + r;
                    const int b = m >> 11, t = m & 2047;
                    const size_t bh = (size_t)(b * NHEADS + head);
                    ob[(size_t)mat * QKV_PER + (bh * T_SZ + t) * HEADD + hd] =
                        f2bf((acc[ms][ns][r] + bv) * qs);
                }
            }
        }
    }
}

// ---------------------------------------------------------------------------
// bf16 MFMA flash attention with async-STAGE split (T14): issue tile kt+1's
// global K/V loads into registers BEFORE computing tile kt; ds_write after
// the post-compute barrier. Softmax in base-2 (q pre-scaled by QSCALE).
// s_setprio(1) around MFMA clusters (T5). Structure otherwise as round 2/3.
// ---------------------------------------------------------------------------
__global__ __launch_bounds__(256) void attn_mfma_k(
    const ushort* __restrict__ Qb, const ushort* __restrict__ Kb,
    const ushort* __restrict__ Vtb, ushort* __restrict__ Out)
{
    __shared__ ushort Ks[64 * 64];   // [kv][d]  swizzled (chunk ^= row&7)
    __shared__ ushort Vs[64 * 64];   // [d][kv]  swizzled (V^T)

    const int qb = blockIdx.x;
    const int bh = blockIdx.y;
    const int bb = bh / NHEADS, head = bh % NHEADS;
    const int tid = threadIdx.x;
    const int w = tid >> 6, l = tid & 63;
    const int g = l >> 4, r16 = l & 15;
    const int q0 = qb * 64;
    const ushort* Kg = Kb + (size_t)bh * T_SZ * HEADD;
    const ushort* Vg = Vtb + (size_t)bh * HEADD * T_SZ;

    bf16x8 qf[2];
    {
        const ushort* qp = Qb + (size_t)bh * T_SZ * HEADD +
                           (size_t)(q0 + 16 * w + r16) * HEADD + g * 8;
        qf[0] = *(const bf16x8*)(qp);
        qf[1] = *(const bf16x8*)(qp + 32);
    }

    f32x4 o[4];
#pragma unroll
    for (int dc = 0; dc < 4; ++dc) o[dc] = (f32x4){0.f, 0.f, 0.f, 0.f};
    float mR = -1e30f, lR = 0.f;

    // staging slot (2 per thread): row = (tid+256u)>>3, chunk c8 = tid&7
    bf16x8 kr[2], vr[2];
#pragma unroll
    for (int u = 0; u < 2; ++u) {
        int f = tid + 256 * u; int row = f >> 3, c8 = f & 7;
        kr[u] = *(const bf16x8*)(Kg + (size_t)row * HEADD + c8 * 8);
        vr[u] = *(const bf16x8*)(Vg + (size_t)row * T_SZ + c8 * 8);
    }
#pragma unroll
    for (int u = 0; u < 2; ++u) {
        int f = tid + 256 * u; int row = f >> 3, c8 = f & 7;
        int dst = ((c8 ^ (row & 7)) * 8);
        *(bf16x8*)&Ks[row * 64 + dst] = kr[u];
        *(bf16x8*)&Vs[row * 64 + dst] = vr[u];
    }
    __syncthreads();

    for (int kt = 0; kt <= qb; ++kt) {
        // T14: issue next tile's global loads now; latency hides under compute
        if (kt < qb) {
            const int k1 = (kt + 1) * 64;
#pragma unroll
            for (int u = 0; u < 2; ++u) {
                int f = tid + 256 * u; int row = f >> 3, c8 = f & 7;
                kr[u] = *(const bf16x8*)(Kg + (size_t)(k1 + row) * HEADD + c8 * 8);
                vr[u] = *(const bf16x8*)(Vg + (size_t)row * T_SZ + k1 + c8 * 8);
            }
        }

        // S^T[kv][q] for tile kt
        f32x4 st[4];
        __builtin_amdgcn_s_setprio(1);
#pragma unroll
        for (int kc = 0; kc < 4; ++kc) {
            int row = kc * 16 + r16;
            const ushort* krow = &Ks[row * 64];
            bf16x8 a0 = *(const bf16x8*)(krow + ((g    ) ^ (row & 7)) * 8);
            bf16x8 a1 = *(const bf16x8*)(krow + ((g + 4) ^ (row & 7)) * 8);
            f32x4 c = (f32x4){0.f, 0.f, 0.f, 0.f};
            c = __builtin_amdgcn_mfma_f32_16x16x32_bf16(a0, qf[0], c, 0, 0, 0);
            c = __builtin_amdgcn_mfma_f32_16x16x32_bf16(a1, qf[1], c, 0, 0, 0);
            st[kc] = c;
        }
        __builtin_amdgcn_s_setprio(0);

        if (kt == qb) {
            const int qloc = 16 * w + r16;
#pragma unroll
            for (int kc = 0; kc < 4; ++kc)
#pragma unroll
                for (int r = 0; r < 4; ++r)
                    if (kc * 16 + 4 * g + r > qloc) st[kc][r] = -1e30f;
        }

        // online softmax (base 2), lane owns q = r16 within its group
        float pm = -1e30f;
#pragma unroll
        for (int kc = 0; kc < 4; ++kc)
#pragma unroll
            for (int r = 0; r < 4; ++r) pm = fmaxf(pm, st[kc][r]);
        pm = fmaxf(pm, __shfl_xor(pm, 16));
        pm = fmaxf(pm, __shfl_xor(pm, 32));
        float mNew = fmaxf(mR, pm);
        float sc = exp2f(mR - mNew);
        float p[16];
        float rs = 0.f;
#pragma unroll
        for (int kc = 0; kc < 4; ++kc)
#pragma unroll
            for (int r = 0; r < 4; ++r) {
                float e = exp2f(st[kc][r] - mNew);
                p[kc * 4 + r] = e;
                rs += e;
            }
        rs += __shfl_xor(rs, 16);
        rs += __shfl_xor(rs, 32);
        lR = lR * sc + rs;
        mR = mNew;
#pragma unroll
        for (int dc = 0; dc < 4; ++dc) o[dc] *= sc;

        uint pk[4][2];
#pragma unroll
        for (int kc = 0; kc < 4; ++kc) {
            pk[kc][0] = (uint)f2bf(p[kc * 4 + 0]) | ((uint)f2bf(p[kc * 4 + 1]) << 16);
            pk[kc][1] = (uint)f2bf(p[kc * 4 + 2]) | ((uint)f2bf(p[kc * 4 + 3]) << 16);
        }

        const int srcLo = ((g & 1) << 5) | r16;
        const int srcHi = srcLo + 16;
        const bool hiSel = (g >> 1) != 0;
        bf16x8 pb[2];
#pragma unroll
        for (int s = 0; s < 2; ++s) {
            uint A0 = (uint)__shfl((int)pk[2 * s][0],     srcLo);
            uint A1 = (uint)__shfl((int)pk[2 * s][1],     srcLo);
            uint B0 = (uint)__shfl((int)pk[2 * s + 1][0], srcLo);
            uint B1 = (uint)__shfl((int)pk[2 * s + 1][1], srcLo);
            uint A2 = (uint)__shfl((int)pk[2 * s][0],     srcHi);
            uint A3 = (uint)__shfl((int)pk[2 * s][1],     srcHi);
            uint B2 = (uint)__shfl((int)pk[2 * s + 1][0], srcHi);
            uint B3 = (uint)__shfl((int)pk[2 * s + 1][1], srcHi);
            union { uint u[4]; bf16x8 v; } t;
            t.u[0] = hiSel ? B0 : A0;
            t.u[1] = hiSel ? B1 : A1;
            t.u[2] = hiSel ? B2 : A2;
            t.u[3] = hiSel ? B3 : A3;
            pb[s] = t.v;
        }

        __builtin_amdgcn_s_setprio(1);
#pragma unroll
        for (int dc = 0; dc < 4; ++dc) {
            int row = dc * 16 + r16;
            const ushort* vrow = &Vs[row * 64];
            bf16x8 v0 = *(const bf16x8*)(vrow + ((g    ) ^ (row & 7)) * 8);
            bf16x8 v1 = *(const bf16x8*)(vrow + ((g + 4) ^ (row & 7)) * 8);
            o[dc] = __builtin_amdgcn_mfma_f32_16x16x32_bf16(v0, pb[0], o[dc], 0, 0, 0);
            o[dc] = __builtin_amdgcn_mfma_f32_16x16x32_bf16(v1, pb[1], o[dc], 0, 0, 0);
        }
        __builtin_amdgcn_s_setprio(0);

        __syncthreads();               // all waves done reading tile kt
        if (kt < qb) {
#pragma unroll
            for (int u = 0; u < 2; ++u) {
                int f = tid + 256 * u; int row = f >> 3, c8 = f & 7;
                int dst = ((c8 ^ (row & 7)) * 8);
                *(bf16x8*)&Ks[row * 64 + dst] = kr[u];
                *(bf16x8*)&Vs[row * 64 + dst] = vr[u];
            }
            __syncthreads();           // tile kt+1 ready
        }
    }

    // epilogue: att bf16 [b][t=q][head*64 + d]
    const float inv = 1.f / lR;
    const int q = q0 + 16 * w + r16;
    ushort* orow = Out + ((size_t)(bb * T_SZ + q)) * EMBEDC + head * HEADD;
#pragma unroll
    for (int dc = 0; dc < 4; ++dc)
#pragma unroll
        for (int r = 0; r < 4; ++r)
            orow[dc * 16 + 4 * g + r] = f2bf(o[dc][r] * inv);
}

// ---------------------------------------------------------------------------
extern "C" void kernel_launch(void* const* d_in, const int* in_sizes, int n_in,
                              void* d_out, int out_size, void* d_ws, size_t ws_size,
                              hipStream_t stream)
{
    const float* x      = (const float*)d_in[0];   // [2,2048,768]
    const float* w_attn = (const float*)d_in[1];   // [768,2304]
    const float* b_attn = (const float*)d_in[2];   // [2304]
    const float* w_proj = (const float*)d_in[3];   // [768,768]
    const float* b_proj = (const float*)d_in[4];   // [768]
    float* out = (float*)d_out;                    // [2,2048,768] f32

    // Workspace (ushort units): q,k,v | vT | att | x_bf | w_attnT' | w_projT
    ushort* qw   = (ushort*)d_ws;                  // 3*QKV_PER  [mat][bh][t][hd]
    ushort* vT   = qw + (size_t)3 * QKV_PER;       // QKV_PER    [bh][hd][t]
    ushort* attb = vT + QKV_PER;                   // QKV_PER
    ushort* xb   = attb + QKV_PER;                 // QKV_PER
    ushort* waT  = xb + QKV_PER;                   // 768*2304 (col-permuted)
    ushort* wpT  = waT + (size_t)EMBEDC * 3 * EMBEDC;

    cast_k<<<QKV_PER / (256 * 8), 256, 0, stream>>>(x, xb, QKV_PER);
    tcast_k<1><<<dim3(3 * EMBEDC / 32, EMBEDC / 32), 256, 0, stream>>>(
        w_attn, waT, EMBEDC, 3 * EMBEDC);
    tcast_k<0><<<dim3(EMBEDC / 32, EMBEDC / 32), 256, 0, stream>>>(
        w_proj, wpT, EMBEDC, EMBEDC);

    // K1: qkv = x @ w_attn + b_attn -> bf16 q/k/v [bh][t][hd] (coalesced)
    gemm_bf16_k<1><<<dim3(2304 / 128, 4096 / 128), 256, 0, stream>>>(
        xb, waT, b_attn, qw, NB * T_SZ, 3 * EMBEDC, EMBEDC);

    // V transpose -> [bh][hd][t]
    vt_k<<<dim3(T_SZ / 64, NB * NHEADS), 256, 0, stream>>>(
        qw + 2 * (size_t)QKV_PER, vT);

    // K2: bf16 MFMA causal flash attention -> bf16 att
    attn_mfma_k<<<dim3(T_SZ / 64, NB * NHEADS), 256, 0, stream>>>(
        qw, qw + QKV_PER, vT, attb);

    // K3: out = att @ w_proj + b_proj (f32 out)
    gemm_bf16_k<0><<<dim3(768 / 128, 4096 / 128), 256, 0, stream>>>(
        attb, wpT, b_proj, out, NB * T_SZ, EMBEDC, EMBEDC);
}

// Round 5
// 131.356 us; speedup vs baseline: 7.0720x; 1.0503x over previous
//
#include <hip/hip_runtime.h>
#include <hip/hip_bf16.h>
#include <math.h>

// Problem constants (GPT2Attention: B=2, T=2048, EMBED=768, 12 heads, head=64)
#define NB      2
#define T_SZ    2048
#define EMBEDC  768
#define NHEADS  12
#define HEADD   64
#define QKV_PER (NB * NHEADS * T_SZ * HEADD)   // 3,145,728 elems per q/k/v
// q pre-scale: HEAD^-0.5 * log2(e), so softmax can use exp2 directly
#define QSCALE  0.18033688011112042f

typedef __bf16 bf16x8 __attribute__((ext_vector_type(8)));
typedef float  f32x4  __attribute__((ext_vector_type(4)));

__device__ inline ushort f2bf(float x) {
    union { float f; uint u; } v; v.f = x;
    uint r = v.u + 0x7fffu + ((v.u >> 16) & 1u);   // RNE
    return (ushort)(r >> 16);
}

__device__ inline uint pack2bf(float a, float b) {   // native cvt (RNE), 2x bf16
    union { __bf16 h[2]; uint u; } t;
    t.h[0] = (__bf16)a; t.h[1] = (__bf16)b;
    return t.u;
}

__device__ inline void gload16(const ushort* g, ushort* l) {
    __builtin_amdgcn_global_load_lds(
        (const __attribute__((address_space(1))) unsigned int*)g,
        (__attribute__((address_space(3))) unsigned int*)l, 16, 0, 0);
}

// ---------------------------------------------------------------------------
// f32 -> bf16 elementwise cast (8 elems/thread)
// ---------------------------------------------------------------------------
__global__ __launch_bounds__(256) void cast_k(const float* __restrict__ in,
                                              ushort* __restrict__ out, int n)
{
    int i = (blockIdx.x * 256 + threadIdx.x) * 8;
    if (i >= n) return;
    float4 a = *(const float4*)(in + i);
    float4 b = *(const float4*)(in + i + 4);
    union { ushort u[8]; int4 v; } p;
    p.u[0] = f2bf(a.x); p.u[1] = f2bf(a.y); p.u[2] = f2bf(a.z); p.u[3] = f2bf(a.w);
    p.u[4] = f2bf(b.x); p.u[5] = f2bf(b.y); p.u[6] = f2bf(b.z); p.u[7] = f2bf(b.w);
    *(int4*)(out + i) = p.v;
}

// ---------------------------------------------------------------------------
// Transpose-cast: in[R][C] f32 -> out[C'][R] bf16, 32x32 LDS tile.
// PERM=1 relocates output row n -> mat*768 + (c%12)*64 + c/12 (c = n%768),
// so GEMM output columns come out in [mat][head][hd] order.
// ---------------------------------------------------------------------------
template <int PERM>
__global__ __launch_bounds__(256) void tcast_k(const float* __restrict__ in,
                                               ushort* __restrict__ out,
                                               int R, int C)
{
    __shared__ float t[32][33];
    const int c0 = blockIdx.x * 32, r0 = blockIdx.y * 32;
    const int tx = threadIdx.x & 31, ty = threadIdx.x >> 5;
#pragma unroll
    for (int u = 0; u < 4; ++u)
        t[ty + 8 * u][tx] = in[(size_t)(r0 + ty + 8 * u) * C + c0 + tx];
    __syncthreads();
#pragma unroll
    for (int u = 0; u < 4; ++u) {
        int n = c0 + ty + 8 * u;
        int orow = n;
        if (PERM) {
            int mat = n / EMBEDC, cc = n % EMBEDC;
            orow = mat * EMBEDC + (cc % NHEADS) * HEADD + cc / NHEADS;
        }
        out[(size_t)orow * R + r0 + tx] = f2bf(t[tx][ty + 8 * u]);
    }
}

// ---------------------------------------------------------------------------
// V transpose: in [bh][t][hd] bf16 -> out [bh][hd][t] bf16. 64x64 LDS tile.
// ---------------------------------------------------------------------------
__global__ __launch_bounds__(256) void vt_k(const ushort* __restrict__ in,
                                            ushort* __restrict__ out)
{
    __shared__ ushort tile[64][66];
    const int bh = blockIdx.y;
    const int t0 = blockIdx.x * 64;
    const int tid = threadIdx.x;
#pragma unroll
    for (int u = 0; u < 2; ++u) {
        int s = tid + 256 * u;
        int r = s >> 3, c8 = s & 7;
        *(bf16x8*)&tile[r][c8 * 8] =
            *(const bf16x8*)(in + ((size_t)bh * T_SZ + t0 + r) * HEADD + c8 * 8);
    }
    __syncthreads();
#pragma unroll
    for (int u = 0; u < 2; ++u) {
        int s = tid + 256 * u;
        int hd = s >> 3, tt = s & 7;
        union { ushort v[8]; int4 q; } pk;
#pragma unroll
        for (int j = 0; j < 8; ++j) pk.v[j] = tile[tt * 8 + j][hd];
        *(int4*)(out + ((size_t)bh * HEADD + hd) * T_SZ + t0 + tt * 8) = pk.q;
    }
}

// ---------------------------------------------------------------------------
// bf16 MFMA GEMM, 2-PHASE double-buffered (T3 minimum recipe): issue tile
// k+1's global_load_lds BEFORE computing tile k; single barrier per K-step
// (its vmcnt(0) drain lands after the MFMA block -> staging overlaps compute).
// 128x128 tile, BK=32, 4 waves (2x2), 4x4 16x16x32 frags per wave.
// Source chunk pre-swizzled (c ^= row&3) with matching XOR on ds_read (r21).
// MODE 0: f32 store out[m*N+n] = acc + bias[n]
// MODE 1: permuted columns n' = mat*768+head*64+hd -> q(scaled)/k/v at
//         [mat][bh][t][hd]; bias via original n.
// ---------------------------------------------------------------------------
#define STAGE(buf, koff)                                        \
    do {                                                        \
        gload16(gA0 + (koff), &As[buf][lA0o]);                  \
        gload16(gA1 + (koff), &As[buf][lA1o]);                  \
        gload16(gB0 + (koff), &Bs[buf][lB0o]);                  \
        gload16(gB1 + (koff), &Bs[buf][lB1o]);                  \
    } while (0)

template <int MODE>
__global__ __launch_bounds__(256) void gemm_bf16_k(
    const ushort* __restrict__ A, const ushort* __restrict__ Bt,
    const float* __restrict__ bias, void* __restrict__ outp,
    int M, int N, int K)
{
    __shared__ ushort As[2][128 * 32];
    __shared__ ushort Bs[2][128 * 32];

    const int tid = threadIdx.x;
    const int w = tid >> 6, l = tid & 63;
    const int g = l >> 4, r16 = l & 15;
    const int wr = w >> 1, wc = w & 1;
    const int m0 = blockIdx.y * 128, n0 = blockIdx.x * 128;

    const int srow = l >> 2;
    const int scol = ((l & 3) ^ (srow & 3)) * 8;
    const ushort* gA0 = A + (size_t)(m0 + 32 * w + srow) * K + scol;
    const ushort* gA1 = gA0 + (size_t)16 * K;
    const ushort* gB0 = Bt + (size_t)(n0 + 32 * w + srow) * K + scol;
    const ushort* gB1 = gB0 + (size_t)16 * K;
    const int lA0o = (32 * w) * 32,      lA1o = (32 * w + 16) * 32;
    const int lB0o = lA0o,               lB1o = lA1o;

    f32x4 acc[4][4];
#pragma unroll
    for (int i = 0; i < 4; ++i)
#pragma unroll
        for (int j = 0; j < 4; ++j) acc[i][j] = (f32x4){0.f, 0.f, 0.f, 0.f};

    const int rck = (r16 & 3);

    STAGE(0, 0);
    __syncthreads();                       // buf0 landed

    int cur = 0;
    for (int k0 = 0; k0 < K; k0 += 32) {
        if (k0 + 32 < K) STAGE(cur ^ 1, k0 + 32);   // in flight during MFMA

        const ushort* sA = As[cur];
        const ushort* sB = Bs[cur];
        bf16x8 af[4], bfr[4];
#pragma unroll
        for (int ms = 0; ms < 4; ++ms) {
            int row = 64 * wr + 16 * ms + r16;
            af[ms] = *(const bf16x8*)&sA[row * 32 + ((g ^ rck) * 8)];
        }
#pragma unroll
        for (int ns = 0; ns < 4; ++ns) {
            int row = 64 * wc + 16 * ns + r16;
            bfr[ns] = *(const bf16x8*)&sB[row * 32 + ((g ^ rck) * 8)];
        }
#pragma unroll
        for (int ms = 0; ms < 4; ++ms)
#pragma unroll
            for (int ns = 0; ns < 4; ++ns)
                acc[ms][ns] = __builtin_amdgcn_mfma_f32_16x16x32_bf16(
                    af[ms], bfr[ns], acc[ms][ns], 0, 0, 0);

        __syncthreads();                   // next buf landed + readers done
        cur ^= 1;
    }

#pragma unroll
    for (int ns = 0; ns < 4; ++ns) {
        const int n = n0 + 64 * wc + 16 * ns + r16;
        if (MODE == 0) {
            float* out = (float*)outp;
            const float bv = bias[n];
#pragma unroll
            for (int ms = 0; ms < 4; ++ms) {
                const int mb = m0 + 64 * wr + 16 * ms + 4 * g;
#pragma unroll
                for (int r = 0; r < 4; ++r)
                    out[(size_t)(mb + r) * N + n] = acc[ms][ns][r] + bv;
            }
        } else {
            ushort* ob = (ushort*)outp;
            const int mat  = n / EMBEDC;   // n is the PERMUTED column n'
            const int c    = n - mat * EMBEDC;
            const int head = c >> 6;
            const int hd   = c & 63;
            const float bv = bias[mat * EMBEDC + hd * NHEADS + head];
            const float qs = (mat == 0) ? QSCALE : 1.f;
#pragma unroll
            for (int ms = 0; ms < 4; ++ms) {
                const int mb = m0 + 64 * wr + 16 * ms + 4 * g;
#pragma unroll
                for (int r = 0; r < 4; ++r) {
                    const int m = mb + r;
                    const int b = m >> 11, t = m & 2047;
                    const size_t bh = (size_t)(b * NHEADS + head);
                    ob[(size_t)mat * QKV_PER + (bh * T_SZ + t) * HEADD + hd] =
                        f2bf((acc[ms][ns][r] + bv) * qs);
                }
            }
        }
    }
}

// ---------------------------------------------------------------------------
// bf16 MFMA flash attention, KV-tile = 128 (fixed softmax chain amortized 2x),
// reg-prefetch staging (T14), defer-max (T13, THR=8 in log2 domain), no
// setprio. Grid (T/64, B*NHEADS), 256 thr = 4 waves; wave w: q rows 16w..+15.
// S^T = mfma(A=K, B=Q^T); per-lane online softmax over 32 kv; P^T -> B-frags
// via 32 fixed-pattern __shfl; O^T += mfma(A=V^T, B=P^T).
// LDS: Ks[128][64] chunk^=row&7; Vs[64][128] chunk^=row&15 (both-sides XOR).
// ---------------------------------------------------------------------------
__global__ __launch_bounds__(256, 3) void attn_mfma_k(
    const ushort* __restrict__ Qb, const ushort* __restrict__ Kb,
    const ushort* __restrict__ Vtb, ushort* __restrict__ Out)
{
    __shared__ ushort Ks[128 * 64];   // [kv][d]
    __shared__ ushort Vs[64 * 128];   // [d][kv]

    const int qb = blockIdx.x;        // 0..31
    const int bh = blockIdx.y;
    const int bb = bh / NHEADS, head = bh % NHEADS;
    const int tid = threadIdx.x;
    const int w = tid >> 6, l = tid & 63;
    const int g = l >> 4, r16 = l & 15;
    const int q0 = qb * 64;
    const int nt = qb / 2 + 1;        // ceil((qb+1)*64 / 128)
    const ushort* Kg = Qb ? Kb + (size_t)bh * T_SZ * HEADD : nullptr;
    const ushort* Vg = Vtb + (size_t)bh * HEADD * T_SZ;

    bf16x8 qf[2];
    {
        const ushort* qp = Qb + (size_t)bh * T_SZ * HEADD +
                           (size_t)(q0 + 16 * w + r16) * HEADD + g * 8;
        qf[0] = *(const bf16x8*)(qp);
        qf[1] = *(const bf16x8*)(qp + 32);
    }

    f32x4 o[4];
#pragma unroll
    for (int dc = 0; dc < 4; ++dc) o[dc] = (f32x4){0.f, 0.f, 0.f, 0.f};
    float mR = -1e30f, lR = 0.f;

    // staging slots: K: s=tid+256u -> row=s>>3 (128), c8=s&7
    //                V: row=d=s>>4 (64), c16=s&15
    bf16x8 kr[4], vr[4];
#pragma unroll
    for (int u = 0; u < 4; ++u) {
        int s = tid + 256 * u;
        kr[u] = *(const bf16x8*)(Kg + (size_t)(s >> 3) * HEADD + (s & 7) * 8);
        vr[u] = *(const bf16x8*)(Vg + (size_t)(s >> 4) * T_SZ + (s & 15) * 8);
    }
#pragma unroll
    for (int u = 0; u < 4; ++u) {
        int s = tid + 256 * u;
        int krow = s >> 3, kc8 = s & 7;
        int vrow = s >> 4, vc16 = s & 15;
        *(bf16x8*)&Ks[krow * 64 + ((kc8 ^ (krow & 7)) * 8)] = kr[u];
        *(bf16x8*)&Vs[vrow * 128 + ((vc16 ^ (vrow & 15)) * 8)] = vr[u];
    }
    __syncthreads();

    const int srcLo = ((g & 1) << 5) | r16;
    const int srcHi = srcLo + 16;
    const bool hiSel = (g >> 1) != 0;
    const int qg = q0 + 16 * w + r16;

    for (int kt = 0; kt < nt; ++kt) {
        // T14: prefetch next tile into regs; hides under this tile's compute
        if (kt + 1 < nt) {
            const int k1 = (kt + 1) * 128;
#pragma unroll
            for (int u = 0; u < 4; ++u) {
                int s = tid + 256 * u;
                kr[u] = *(const bf16x8*)(Kg + (size_t)(k1 + (s >> 3)) * HEADD +
                                         (s & 7) * 8);
                vr[u] = *(const bf16x8*)(Vg + (size_t)(s >> 4) * T_SZ + k1 +
                                         (s & 15) * 8);
            }
        }

        // S^T[kv][q]: 8 kv-subtiles x (2 MFMAs over d)
        f32x4 st[8];
#pragma unroll
        for (int kc = 0; kc < 8; ++kc) {
            int row = kc * 16 + r16;
            const ushort* krow = &Ks[row * 64];
            bf16x8 a0 = *(const bf16x8*)(krow + ((g    ) ^ (row & 7)) * 8);
            bf16x8 a1 = *(const bf16x8*)(krow + ((g + 4) ^ (row & 7)) * 8);
            f32x4 c = (f32x4){0.f, 0.f, 0.f, 0.f};
            c = __builtin_amdgcn_mfma_f32_16x16x32_bf16(a0, qf[0], c, 0, 0, 0);
            c = __builtin_amdgcn_mfma_f32_16x16x32_bf16(a1, qf[1], c, 0, 0, 0);
            st[kc] = c;
        }

        if (kt == nt - 1) {               // partial tile: per-element mask
            const int k0 = kt * 128;
#pragma unroll
            for (int kc = 0; kc < 8; ++kc)
#pragma unroll
                for (int r = 0; r < 4; ++r)
                    if (k0 + kc * 16 + 4 * g + r > qg) st[kc][r] = -1e30f;
        }

        // online softmax over 32 kv (base 2); lane owns q = qg
        float pm = -1e30f;
#pragma unroll
        for (int kc = 0; kc < 8; ++kc)
#pragma unroll
            for (int r = 0; r < 4; ++r) pm = fmaxf(pm, st[kc][r]);
        pm = fmaxf(pm, __shfl_xor(pm, 16));
        pm = fmaxf(pm, __shfl_xor(pm, 32));
        if (!__all(pm - mR <= 8.f)) {     // T13 defer-max
            float mNew = fmaxf(mR, pm);
            float sc = exp2f(mR - mNew);
            lR *= sc;
#pragma unroll
            for (int dc = 0; dc < 4; ++dc) o[dc] *= sc;
            mR = mNew;
        }
        float rs = 0.f;
#pragma unroll
        for (int kc = 0; kc < 8; ++kc)
#pragma unroll
            for (int r = 0; r < 4; ++r) {
                float e = exp2f(st[kc][r] - mR);
                st[kc][r] = e;
                rs += e;
            }
        rs += __shfl_xor(rs, 16);
        rs += __shfl_xor(rs, 32);
        lR += rs;

        // pack P^T pairs (native cvt_pk)
        uint pk[8][2];
#pragma unroll
        for (int kc = 0; kc < 8; ++kc) {
            pk[kc][0] = pack2bf(st[kc][0], st[kc][1]);
            pk[kc][1] = pack2bf(st[kc][2], st[kc][3]);
        }

        // per 32-kv group: redistribute to B-frag, then 4 PV MFMAs
#pragma unroll
        for (int s = 0; s < 4; ++s) {
            uint A0 = (uint)__shfl((int)pk[2 * s][0],     srcLo);
            uint A1 = (uint)__shfl((int)pk[2 * s][1],     srcLo);
            uint B0 = (uint)__shfl((int)pk[2 * s + 1][0], srcLo);
            uint B1 = (uint)__shfl((int)pk[2 * s + 1][1], srcLo);
            uint A2 = (uint)__shfl((int)pk[2 * s][0],     srcHi);
            uint A3 = (uint)__shfl((int)pk[2 * s][1],     srcHi);
            uint B2 = (uint)__shfl((int)pk[2 * s + 1][0], srcHi);
            uint B3 = (uint)__shfl((int)pk[2 * s + 1][1], srcHi);
            union { uint u[4]; bf16x8 v; } t;
            t.u[0] = hiSel ? B0 : A0;
            t.u[1] = hiSel ? B1 : A1;
            t.u[2] = hiSel ? B2 : A2;
            t.u[3] = hiSel ? B3 : A3;
#pragma unroll
            for (int dc = 0; dc < 4; ++dc) {
                int row = dc * 16 + r16;
                bf16x8 vf = *(const bf16x8*)
                    &Vs[row * 128 + (((4 * s + g) ^ (row & 15)) * 8)];
                o[dc] = __builtin_amdgcn_mfma_f32_16x16x32_bf16(
                    vf, t.v, o[dc], 0, 0, 0);
            }
        }

        __syncthreads();                  // all waves done reading tile kt
        if (kt + 1 < nt) {
#pragma unroll
            for (int u = 0; u < 4; ++u) {
                int s = tid + 256 * u;
                int krow = s >> 3, kc8 = s & 7;
                int vrow = s >> 4, vc16 = s & 15;
                *(bf16x8*)&Ks[krow * 64 + ((kc8 ^ (krow & 7)) * 8)] = kr[u];
                *(bf16x8*)&Vs[vrow * 128 + ((vc16 ^ (vrow & 15)) * 8)] = vr[u];
            }
            __syncthreads();              // tile kt+1 ready
        }
    }

    // epilogue: att bf16 [b][t=q][head*64 + d], d = dc*16+4g+r
    const float inv = 1.f / lR;
    ushort* orow = Out + ((size_t)(bb * T_SZ + qg)) * EMBEDC + head * HEADD;
#pragma unroll
    for (int dc = 0; dc < 4; ++dc)
#pragma unroll
        for (int r = 0; r < 4; ++r)
            orow[dc * 16 + 4 * g + r] = f2bf(o[dc][r] * inv);
}

// ---------------------------------------------------------------------------
extern "C" void kernel_launch(void* const* d_in, const int* in_sizes, int n_in,
                              void* d_out, int out_size, void* d_ws, size_t ws_size,
                              hipStream_t stream)
{
    const float* x      = (const float*)d_in[0];   // [2,2048,768]
    const float* w_attn = (const float*)d_in[1];   // [768,2304]
    const float* b_attn = (const float*)d_in[2];   // [2304]
    const float* w_proj = (const float*)d_in[3];   // [768,768]
    const float* b_proj = (const float*)d_in[4];   // [768]
    float* out = (float*)d_out;                    // [2,2048,768] f32

    // Workspace (ushort units): q,k,v | vT | att | x_bf | w_attnT' | w_projT
    ushort* qw   = (ushort*)d_ws;                  // 3*QKV_PER  [mat][bh][t][hd]
    ushort* vT   = qw + (size_t)3 * QKV_PER;       // QKV_PER    [bh][hd][t]
    ushort* attb = vT + QKV_PER;                   // QKV_PER
    ushort* xb   = attb + QKV_PER;                 // QKV_PER
    ushort* waT  = xb + QKV_PER;                   // 768*2304 (col-permuted)
    ushort* wpT  = waT + (size_t)EMBEDC * 3 * EMBEDC;

    cast_k<<<QKV_PER / (256 * 8), 256, 0, stream>>>(x, xb, QKV_PER);
    tcast_k<1><<<dim3(3 * EMBEDC / 32, EMBEDC / 32), 256, 0, stream>>>(
        w_attn, waT, EMBEDC, 3 * EMBEDC);
    tcast_k<0><<<dim3(EMBEDC / 32, EMBEDC / 32), 256, 0, stream>>>(
        w_proj, wpT, EMBEDC, EMBEDC);

    // K1: qkv = x @ w_attn + b_attn -> bf16 q/k/v [bh][t][hd]
    gemm_bf16_k<1><<<dim3(2304 / 128, 4096 / 128), 256, 0, stream>>>(
        xb, waT, b_attn, qw, NB * T_SZ, 3 * EMBEDC, EMBEDC);

    // V transpose -> [bh][hd][t]
    vt_k<<<dim3(T_SZ / 64, NB * NHEADS), 256, 0, stream>>>(
        qw + 2 * (size_t)QKV_PER, vT);

    // K2: bf16 MFMA causal flash attention -> bf16 att
    attn_mfma_k<<<dim3(T_SZ / 64, NB * NHEADS), 256, 0, stream>>>(
        qw, qw + QKV_PER, vT, attb);

    // K3: out = att @ w_proj + b_proj (f32 out)
    gemm_bf16_k<0><<<dim3(768 / 128, 4096 / 128), 256, 0, stream>>>(
        attb, wpT, b_proj, out, NB * T_SZ, EMBEDC, EMBEDC);
}